// Round 2
// baseline (17.622 us; speedup 1.0000x reference)
//
#include <hip/hip_runtime.h>
#include <hip/hip_bf16.h>

#define NGRAPH 64
#define NPER   128
#define DIM    256

typedef __attribute__((ext_vector_type(8))) short bf16x8;
typedef __attribute__((ext_vector_type(4))) float f32x4;

__device__ __forceinline__ short f2bf(float f) {
    union { float f; unsigned u; } v; v.f = f;
    unsigned u = v.u + (0x7FFFu + ((v.u >> 16) & 1u));  // RNE to bf16
    return (short)(u >> 16);
}

// softmax-stat merge: (m,se,ws) where se = sum exp(S-m), ws = sum exp(S-m)*S
__device__ __forceinline__ void sm_merge(float& m, float& se, float& ws,
                                         float mo, float seo, float wso) {
    const float M = fmaxf(m, mo);
    const float a = __expf(m - M), b = __expf(mo - M);
    se = a * se + b * seo;
    ws = a * ws + b * wso;
    m = M;
}

// ---------------- Kernel 1: per-quadrant scores + partial softmax stats ----
// Block b: g = b>>2, qi = (b>>1)&1 (L row-half), qj = b&1 (R row-half).
// Computes S_q = Lq Rq^T (64x64, K=256) via MFMA, then writes per-row and
// per-col partial (m, sum-exp, weighted-sum) triples to ws3.
// ws3 layout: [side][g][part][node] * 3 floats,
//   side0 (L rows): part = qj, node = qi*64 + r
//   side1 (R cols): part = qi, node = qj*64 + j
__global__ __launch_bounds__(512, 1)
void quad_stats_kernel(const float* __restrict__ left,
                       const float* __restrict__ right,
                       float* __restrict__ ws3) {
    __shared__ __align__(16) short Ls[64 * DIM];   // bf16 swizzled, 32 KB
    __shared__ __align__(16) short Rs[64 * DIM];   // bf16 swizzled, 32 KB
    __shared__ float rowpart[2][64][3];            // per col-half partial row stats
    __shared__ float colpart[4][64][3];            // per row-strip partial col stats

    const int b  = blockIdx.x;
    const int g  = b >> 2;
    const int qi = (b >> 1) & 1;
    const int qj = b & 1;
    const float* Lq = left  + ((size_t)g * NPER + qi * 64) * DIM;
    const float* Rq = right + ((size_t)g * NPER + qj * 64) * DIM;

    const int tid = threadIdx.x;

    // stage both 64x256 fp32 panels -> bf16 LDS (row stride 512B, XOR swizzle)
    for (int c = tid; c < 2 * 64 * (DIM / 8); c += 512) {
        const int which = c >> 11;           // 0 = L, 1 = R
        const int cc    = c & 2047;
        const int row   = cc >> 5;
        const int k8    = cc & 31;
        const float* src = (which ? Rq : Lq) + row * DIM + k8 * 8;
        const float4 f0 = *(const float4*)(src);
        const float4 f1 = *(const float4*)(src + 4);
        bf16x8 h;
        h[0] = f2bf(f0.x); h[1] = f2bf(f0.y); h[2] = f2bf(f0.z); h[3] = f2bf(f0.w);
        h[4] = f2bf(f1.x); h[5] = f2bf(f1.y); h[6] = f2bf(f1.z); h[7] = f2bf(f1.w);
        short* dst = which ? Rs : Ls;
        const int byte = row * (DIM * 2) + ((k8 * 16) ^ ((row & 7) << 4));
        *(bf16x8*)((char*)dst + byte) = h;
    }
    __syncthreads();

    // 8 waves: wave = (strip 0..3 of 16 L-rows) x (col-half 0..1 of 32 R-cols)
    const int wave  = tid >> 6;
    const int lane  = tid & 63;
    const int strip = wave & 3;
    const int ch    = wave >> 2;
    const int row0  = strip * 16;
    const int lr    = lane & 15;
    const int lkb   = (lane >> 4) * 16;

    f32x4 acc[2];
    acc[0] = (f32x4){0.f, 0.f, 0.f, 0.f};
    acc[1] = (f32x4){0.f, 0.f, 0.f, 0.f};

    const int arow = row0 + lr;
    const char* aBase = (const char*)Ls + arow * (DIM * 2);
    const int aswz = (arow & 7) << 4;

    #pragma unroll
    for (int ks = 0; ks < 8; ++ks) {
        const bf16x8 a = *(const bf16x8*)(aBase + ((ks * 64 + lkb) ^ aswz));
        #pragma unroll
        for (int c = 0; c < 2; ++c) {
            const int brow = ch * 32 + c * 16 + lr;
            const bf16x8 bb = *(const bf16x8*)((const char*)Rs + brow * (DIM * 2)
                                               + ((ks * 64 + lkb) ^ ((brow & 7) << 4)));
            acc[c] = __builtin_amdgcn_mfma_f32_16x16x32_bf16(a, bb, acc[c], 0, 0, 0);
        }
    }

    // --- partial ROW stats (over this wave's 32 cols) ---
    // C layout: lane holds S[row0 + (lane>>4)*4 + r][ch*32 + c*16 + (lane&15)]
    #pragma unroll
    for (int r = 0; r < 4; ++r) {
        float m = fmaxf(acc[0][r], acc[1][r]);
        #pragma unroll
        for (int off = 1; off < 16; off <<= 1) m = fmaxf(m, __shfl_xor(m, off, 64));
        float se = 0.f, wsum = 0.f;
        #pragma unroll
        for (int c = 0; c < 2; ++c) {
            const float e = __expf(acc[c][r] - m);
            se += e; wsum += e * acc[c][r];
        }
        #pragma unroll
        for (int off = 1; off < 16; off <<= 1) {
            se   += __shfl_xor(se, off, 64);
            wsum += __shfl_xor(wsum, off, 64);
        }
        if ((lane & 15) == 0) {
            const int rr = row0 + (lane >> 4) * 4 + r;
            rowpart[ch][rr][0] = m; rowpart[ch][rr][1] = se; rowpart[ch][rr][2] = wsum;
        }
    }

    // --- partial COL stats (over this wave's 16 rows) ---
    #pragma unroll
    for (int c = 0; c < 2; ++c) {
        float m = fmaxf(fmaxf(acc[c][0], acc[c][1]), fmaxf(acc[c][2], acc[c][3]));
        float se = 0.f, wsum = 0.f;
        #pragma unroll
        for (int r = 0; r < 4; ++r) {
            const float e = __expf(acc[c][r] - m);
            se += e; wsum += e * acc[c][r];
        }
        #pragma unroll
        for (int off = 16; off < 64; off <<= 1) {
            const float mo  = __shfl_xor(m, off, 64);
            const float seo = __shfl_xor(se, off, 64);
            const float wso = __shfl_xor(wsum, off, 64);
            sm_merge(m, se, wsum, mo, seo, wso);
        }
        if (lane < 16) {
            const int j = ch * 32 + c * 16 + lr;
            colpart[strip][j][0] = m; colpart[strip][j][1] = se; colpart[strip][j][2] = wsum;
        }
    }
    __syncthreads();

    // --- merge partials, write triples to ws3 ---
    if (tid < 64) {                       // L rows: merge 2 col-halves
        const int r = tid;
        float m = rowpart[0][r][0], se = rowpart[0][r][1], wsum = rowpart[0][r][2];
        sm_merge(m, se, wsum, rowpart[1][r][0], rowpart[1][r][1], rowpart[1][r][2]);
        const size_t o = ((((size_t)0 * NGRAPH + g) * 2 + qj) * NPER + qi * 64 + r) * 3;
        ws3[o] = m; ws3[o + 1] = se; ws3[o + 2] = wsum;
    } else if (tid < 128) {               // R cols: merge 4 row-strips
        const int j = tid - 64;
        float m = colpart[0][j][0], se = colpart[0][j][1], wsum = colpart[0][j][2];
        #pragma unroll
        for (int s = 1; s < 4; ++s)
            sm_merge(m, se, wsum, colpart[s][j][0], colpart[s][j][1], colpart[s][j][2]);
        const size_t o = ((((size_t)1 * NGRAPH + g) * 2 + qi) * NPER + qj * 64 + j) * 3;
        ws3[o] = m; ws3[o + 1] = se; ws3[o + 2] = wsum;
    }
}

// ---------------- Kernel 2: gates + gated fp32 column sums ----------------
__global__ __launch_bounds__(512, 1)
void gate_sum_kernel(const float* __restrict__ left,
                     const float* __restrict__ right,
                     const float* __restrict__ ws3,
                     float* __restrict__ out) {
    __shared__ float gates[NPER];
    __shared__ float red[2][DIM];

    const int b    = blockIdx.x;
    const int side = b & 1;
    const int g    = b >> 1;
    const float* emb = (side ? right : left) + (size_t)g * NPER * DIM;
    float* outp = out + (size_t)side * (NGRAPH * DIM) + (size_t)g * DIM;

    const int tid = threadIdx.x;
    if (tid < NPER) {
        const size_t base = (((size_t)side * NGRAPH + g) * 2) * NPER + tid;
        const size_t o0 = base * 3, o1 = (base + NPER) * 3;
        float m = ws3[o0], se = ws3[o0 + 1], wsum = ws3[o0 + 2];
        sm_merge(m, se, wsum, ws3[o1], ws3[o1 + 1], ws3[o1 + 2]);
        const float gdot = wsum / se;
        gates[tid] = 1.f / (1.f + __expf(-gdot));
    }
    __syncthreads();

    const int d    = tid & 255;
    const int half = tid >> 8;
    float sum = 0.f;
    const float* qbase = emb + (size_t)(half * 64) * DIM + d;
    #pragma unroll 8
    for (int i = 0; i < 64; ++i) sum += gates[half * 64 + i] * qbase[(size_t)i * DIM];
    red[half][d] = sum;
    __syncthreads();
    if (tid < 256) outp[tid] = red[0][tid] + red[1][tid];
}

// ---------------- Fallback (R0 known-good single kernel) ------------------
__global__ __launch_bounds__(512, 1)
void match_gate_kernel(const float* __restrict__ left,
                       const float* __restrict__ right,
                       float* __restrict__ out) {
    __shared__ __align__(16) short Qs[NPER * DIM];
    __shared__ __align__(16) short Ks[NPER * DIM];
    __shared__ float wq[NPER];
    __shared__ float red[2][DIM];

    const int bid  = blockIdx.x;
    const int side = bid & 1;
    const int g    = bid >> 1;
    const float* Qg = (side ? right : left) + (size_t)g * NPER * DIM;
    const float* Kg = (side ? left  : right) + (size_t)g * NPER * DIM;
    float* outp = out + (size_t)side * (NGRAPH * DIM) + (size_t)g * DIM;

    const int tid = threadIdx.x;
    for (int c = tid; c < 2 * NPER * (DIM / 8); c += 512) {
        const int which = c >> 12;
        const int cc    = c & 4095;
        const int row   = cc >> 5;
        const int k8    = cc & 31;
        const float* src = (which ? Kg : Qg) + row * DIM + k8 * 8;
        const float4 f0 = *(const float4*)(src);
        const float4 f1 = *(const float4*)(src + 4);
        bf16x8 h;
        h[0] = f2bf(f0.x); h[1] = f2bf(f0.y); h[2] = f2bf(f0.z); h[3] = f2bf(f0.w);
        h[4] = f2bf(f1.x); h[5] = f2bf(f1.y); h[6] = f2bf(f1.z); h[7] = f2bf(f1.w);
        short* dst = which ? Ks : Qs;
        const int byte = row * (DIM * 2) + ((k8 * 16) ^ ((row & 7) << 4));
        *(bf16x8*)((char*)dst + byte) = h;
    }
    __syncthreads();

    const int wave = tid >> 6;
    const int lane = tid & 63;
    const int row0 = wave * 16;
    const int lr   = lane & 15;
    const int lkb  = (lane >> 4) * 16;

    f32x4 acc[8];
    #pragma unroll
    for (int c = 0; c < 8; ++c) acc[c] = (f32x4){0.f, 0.f, 0.f, 0.f};

    const int arow = row0 + lr;
    const char* aBase = (const char*)Qs + arow * (DIM * 2);
    const int aswz = (arow & 7) << 4;

    #pragma unroll
    for (int ks = 0; ks < 8; ++ks) {
        const bf16x8 a = *(const bf16x8*)(aBase + ((ks * 64 + lkb) ^ aswz));
        #pragma unroll
        for (int c = 0; c < 8; ++c) {
            const int brow = c * 16 + lr;
            const bf16x8 bb = *(const bf16x8*)((const char*)Ks + brow * (DIM * 2)
                                               + ((ks * 64 + lkb) ^ ((brow & 7) << 4)));
            acc[c] = __builtin_amdgcn_mfma_f32_16x16x32_bf16(a, bb, acc[c], 0, 0, 0);
        }
    }

    float wl[4];
    #pragma unroll
    for (int r = 0; r < 4; ++r) {
        float m = acc[0][r];
        #pragma unroll
        for (int c = 1; c < 8; ++c) m = fmaxf(m, acc[c][r]);
        #pragma unroll
        for (int off = 1; off < 16; off <<= 1) m = fmaxf(m, __shfl_xor(m, off, 64));
        float se = 0.f, wsum = 0.f;
        #pragma unroll
        for (int c = 0; c < 8; ++c) {
            const float e = __expf(acc[c][r] - m);
            se += e; wsum += e * acc[c][r];
        }
        #pragma unroll
        for (int off = 1; off < 16; off <<= 1) {
            se += __shfl_xor(se, off, 64);
            wsum += __shfl_xor(wsum, off, 64);
        }
        wl[r] = 1.f / (1.f + __expf(-(wsum / se)));
    }
    if ((lane & 15) == 0) {
        #pragma unroll
        for (int r = 0; r < 4; ++r) wq[row0 + (lane >> 4) * 4 + r] = wl[r];
    }
    __syncthreads();

    const int d    = tid & 255;
    const int half = tid >> 8;
    float sum = 0.f;
    const float* qbase = Qg + (size_t)(half * 64) * DIM + d;
    #pragma unroll 8
    for (int i = 0; i < 64; ++i) sum += wq[half * 64 + i] * qbase[(size_t)i * DIM];
    red[half][d] = sum;
    __syncthreads();
    if (tid < 256) outp[tid] = red[0][tid] + red[1][tid];
}

extern "C" void kernel_launch(void* const* d_in, const int* in_sizes, int n_in,
                              void* d_out, int out_size, void* d_ws, size_t ws_size,
                              hipStream_t stream) {
    const float* left  = (const float*)d_in[0];
    const float* right = (const float*)d_in[1];
    float* out = (float*)d_out;

    const size_t ws_needed = (size_t)2 * NGRAPH * 2 * NPER * 3 * sizeof(float); // 393 KB
    if (ws_size >= ws_needed) {
        float* ws3 = (float*)d_ws;
        quad_stats_kernel<<<NGRAPH * 4, 512, 0, stream>>>(left, right, ws3);
        gate_sum_kernel<<<NGRAPH * 2, 512, 0, stream>>>(left, right, ws3, out);
    } else {
        match_gate_kernel<<<NGRAPH * 2, 512, 0, stream>>>(left, right, out);
    }
}

// Round 3
// 17.316 us; speedup vs baseline: 1.0177x; 1.0177x over previous
//
#include <hip/hip_runtime.h>
#include <hip/hip_bf16.h>

#define NGRAPH 64
#define NPER   128
#define DIM    256

typedef __attribute__((ext_vector_type(8))) short bf16x8;
typedef __attribute__((ext_vector_type(4))) float f32x4;

__device__ __forceinline__ short f2bf(float f) {
    union { float f; unsigned u; } v; v.f = f;
    unsigned u = v.u + (0x7FFFu + ((v.u >> 16) & 1u));  // RNE to bf16
    return (short)(u >> 16);
}
__device__ __forceinline__ float bf2f(short s) {
    union { unsigned u; float f; } v; v.u = ((unsigned)(unsigned short)s) << 16;
    return v.f;
}

// softmax-stat merge: (m,se,ws) with se = sum exp(S-m), ws = sum exp(S-m)*S
__device__ __forceinline__ void sm_merge(float& m, float& se, float& ws,
                                         float mo, float seo, float wso) {
    const float M = fmaxf(m, mo);
    const float a = __expf(m - M), b = __expf(mo - M);
    se = a * se + b * seo;
    ws = a * ws + b * wso;
    m = M;
}

// One block per (graph, side, row-half). Q = 64 rows of this side's panel,
// K = full 128 rows of the other side. Full row softmax (128 cols) -> exact
// gates for the 64 Q rows -> gated column-sum from LDS bf16 -> atomicAdd to out.
// Gate identity: sigmoid(<Q_i, atten_i>) = sigmoid(sum_j p_ij S_ij).
__global__ __launch_bounds__(512, 1)
void half_gate_kernel(const float* __restrict__ left,
                      const float* __restrict__ right,
                      float* __restrict__ out) {
    __shared__ __align__(16) short Qs[64 * DIM];    // bf16 swizzled, 32 KB
    __shared__ __align__(16) short Ks[NPER * DIM];  // bf16 swizzled, 64 KB
    __shared__ float rowpart[2][64][3];             // per col-half partial row stats
    __shared__ float wq[64];                        // gates
    __shared__ float red[2][DIM];                   // epilogue cross-half reduce

    // XCD-grouping swizzle: the 4 blocks of a graph share i&7 (same XCD slot
    // under round-robin dispatch) so the shared K panels get L2 reuse.
    const int i    = blockIdx.x;
    const int g    = (i & 7) * 8 + ((i >> 3) & 7);
    const int q    = i >> 6;           // 0..3
    const int side = q >> 1;
    const int rh   = q & 1;

    const float* Qg = (side ? right : left) + ((size_t)g * NPER + rh * 64) * DIM;
    const float* Kg = (side ? left  : right) + (size_t)g * NPER * DIM;
    float* outp = out + (size_t)side * (NGRAPH * DIM) + (size_t)g * DIM;

    const int tid = threadIdx.x;

    // ---- stage Q (64 rows) + K (128 rows) fp32 -> bf16 LDS, XOR swizzle ----
    for (int c = tid; c < (64 + 128) * (DIM / 8); c += 512) {
        const bool isQ = c < 64 * (DIM / 8);
        const int cc   = isQ ? c : c - 64 * (DIM / 8);
        const int row  = cc >> 5;            // 32 chunks per row
        const int k8   = cc & 31;
        const float* src = (isQ ? Qg : Kg) + row * DIM + k8 * 8;
        const float4 f0 = *(const float4*)(src);
        const float4 f1 = *(const float4*)(src + 4);
        bf16x8 h;
        h[0] = f2bf(f0.x); h[1] = f2bf(f0.y); h[2] = f2bf(f0.z); h[3] = f2bf(f0.w);
        h[4] = f2bf(f1.x); h[5] = f2bf(f1.y); h[6] = f2bf(f1.z); h[7] = f2bf(f1.w);
        short* dst = isQ ? Qs : Ks;
        const int byte = row * (DIM * 2) + ((k8 * 16) ^ ((row & 7) << 4));
        *(bf16x8*)((char*)dst + byte) = h;
    }
    __syncthreads();

    // ---- S = Q K^T: wave = (row-strip 0..3) x (col-half 0..1) ----
    const int wave  = tid >> 6;
    const int lane  = tid & 63;
    const int strip = wave & 3;          // 16 Q rows
    const int ch    = wave >> 2;         // 64 K cols
    const int row0  = strip * 16;
    const int lr    = lane & 15;
    const int lkb   = (lane >> 4) * 16;  // byte offset of lane's k-slice

    f32x4 acc[4];
    #pragma unroll
    for (int c = 0; c < 4; ++c) acc[c] = (f32x4){0.f, 0.f, 0.f, 0.f};

    const int arow = row0 + lr;
    const char* aBase = (const char*)Qs + arow * (DIM * 2);
    const int aswz = (arow & 7) << 4;

    #pragma unroll
    for (int ks = 0; ks < 8; ++ks) {
        const bf16x8 a = *(const bf16x8*)(aBase + ((ks * 64 + lkb) ^ aswz));
        #pragma unroll
        for (int c = 0; c < 4; ++c) {
            const int brow = ch * 64 + c * 16 + lr;
            const bf16x8 bb = *(const bf16x8*)((const char*)Ks + brow * (DIM * 2)
                                               + ((ks * 64 + lkb) ^ ((brow & 7) << 4)));
            acc[c] = __builtin_amdgcn_mfma_f32_16x16x32_bf16(a, bb, acc[c], 0, 0, 0);
        }
    }

    // ---- partial row stats over this wave's 64 cols ----
    // C layout: lane holds S[row0 + (lane>>4)*4 + r][ch*64 + c*16 + (lane&15)]
    #pragma unroll
    for (int r = 0; r < 4; ++r) {
        float m = fmaxf(fmaxf(acc[0][r], acc[1][r]), fmaxf(acc[2][r], acc[3][r]));
        #pragma unroll
        for (int off = 1; off < 16; off <<= 1) m = fmaxf(m, __shfl_xor(m, off, 64));
        float se = 0.f, wsum = 0.f;
        #pragma unroll
        for (int c = 0; c < 4; ++c) {
            const float e = __expf(acc[c][r] - m);
            se += e; wsum += e * acc[c][r];
        }
        #pragma unroll
        for (int off = 1; off < 16; off <<= 1) {
            se   += __shfl_xor(se, off, 64);
            wsum += __shfl_xor(wsum, off, 64);
        }
        if ((lane & 15) == 0) {
            const int rr = row0 + (lane >> 4) * 4 + r;
            rowpart[ch][rr][0] = m; rowpart[ch][rr][1] = se; rowpart[ch][rr][2] = wsum;
        }
    }
    __syncthreads();

    // ---- merge col-halves -> gates ----
    if (tid < 64) {
        float m = rowpart[0][tid][0], se = rowpart[0][tid][1], wsum = rowpart[0][tid][2];
        sm_merge(m, se, wsum, rowpart[1][tid][0], rowpart[1][tid][1], rowpart[1][tid][2]);
        wq[tid] = 1.f / (1.f + __expf(-(wsum / se)));
    }
    __syncthreads();

    // ---- partial[d] = sum_i wq[i] * Q[i][d] from LDS bf16 ----
    const int d    = tid & 255;
    const int half = tid >> 8;
    float sum = 0.f;
    #pragma unroll 8
    for (int i2 = half * 32; i2 < half * 32 + 32; ++i2) {
        const short s = *(const short*)((const char*)Qs + i2 * (DIM * 2)
                                        + ((2 * d) ^ ((i2 & 7) << 4)));
        sum += wq[i2] * bf2f(s);
    }
    red[half][d] = sum;
    __syncthreads();
    if (tid < 256) atomicAdd(&outp[tid], red[0][tid] + red[1][tid]);
}

extern "C" void kernel_launch(void* const* d_in, const int* in_sizes, int n_in,
                              void* d_out, int out_size, void* d_ws, size_t ws_size,
                              hipStream_t stream) {
    const float* left  = (const float*)d_in[0];
    const float* right = (const float*)d_in[1];
    float* out = (float*)d_out;
    hipMemsetAsync(out, 0, (size_t)out_size * sizeof(float), stream);
    half_gate_kernel<<<256, 512, 0, stream>>>(left, right, out);
}

// Round 4
// 13.209 us; speedup vs baseline: 1.3341x; 1.3109x over previous
//
#include <hip/hip_runtime.h>
#include <hip/hip_bf16.h>

#define NGRAPH 64
#define NPER   128
#define DIM    256

typedef __attribute__((ext_vector_type(8))) short bf16x8;
typedef __attribute__((ext_vector_type(4))) float f32x4;

__device__ __forceinline__ float bf2f(short s) {
    union { unsigned u; float f; } v; v.u = ((unsigned)(unsigned short)s) << 16;
    return v.f;
}

__device__ __forceinline__ bf16x8 cvt8(const float4 a, const float4 b) {
    // hardware v_cvt_pk_bf16_f32 via hip intrinsics
    __hip_bfloat162 p0 = __float22bfloat162_rn({a.x, a.y});
    __hip_bfloat162 p1 = __float22bfloat162_rn({a.z, a.w});
    __hip_bfloat162 p2 = __float22bfloat162_rn({b.x, b.y});
    __hip_bfloat162 p3 = __float22bfloat162_rn({b.z, b.w});
    union { __hip_bfloat162 h[4]; bf16x8 v; } u;
    u.h[0] = p0; u.h[1] = p1; u.h[2] = p2; u.h[3] = p3;
    return u.v;
}

// One block per (graph, side, d-half). Full row softmax for this side's 128
// query rows -> exact gates; epilogue writes a disjoint 128-dim output slice
// (no atomics, no memset). Gate: sigmoid(sum_j p_ij S_ij).
// XCD swizzle: the 4 blocks of graph g land on XCD g&7 (L2 panel reuse).
__global__ __launch_bounds__(512, 1)
void match_gate_kernel(const float* __restrict__ left,
                       const float* __restrict__ right,
                       float* __restrict__ out) {
    __shared__ __align__(16) short Ls[NPER * DIM]; // bf16 swizzled, 64 KB
    __shared__ __align__(16) short Rs[NPER * DIM]; // bf16 swizzled, 64 KB
    __shared__ float wq[NPER];
    __shared__ float red[4][128];

    const int j    = blockIdx.x;
    const int g    = (((j >> 5) & 7) << 3) | (j & 7);
    const int sub  = (j >> 3) & 3;
    const int side = sub >> 1;
    const int dh   = sub & 1;

    const float* Lg = left  + (size_t)g * NPER * DIM;
    const float* Rg = right + (size_t)g * NPER * DIM;

    const int tid = threadIdx.x;

    // ---- stage both panels fp32 -> bf16 LDS, 4 batches x (8 loads, 4 writes)
    // chunk c (0..8191): panel = c>>12, row = (c>>5)&127, k8 = c&31
    #pragma unroll
    for (int b = 0; b < 4; ++b) {
        const float* src_panel = (b < 2) ? Lg : Rg;
        short* dst_panel = (b < 2) ? Ls : Rs;
        float4 f[8];
        int row[4], k8[4];
        #pragma unroll
        for (int u = 0; u < 4; ++u) {
            const int cc = (b & 1) * 2048 + u * 512 + tid;  // panel-local chunk
            row[u] = cc >> 5;
            k8[u]  = cc & 31;
            const float* s = src_panel + row[u] * DIM + k8[u] * 8;
            f[2 * u]     = *(const float4*)(s);
            f[2 * u + 1] = *(const float4*)(s + 4);
        }
        #pragma unroll
        for (int u = 0; u < 4; ++u) {
            const bf16x8 h = cvt8(f[2 * u], f[2 * u + 1]);
            const int byte = row[u] * (DIM * 2) + ((k8[u] * 16) ^ ((row[u] & 7) << 4));
            *(bf16x8*)((char*)dst_panel + byte) = h;
        }
    }
    __syncthreads();

    const short* Qs = side ? Rs : Ls;   // this side's panel (rows get gated)
    const short* Ks = side ? Ls : Rs;   // other side

    // ---- S = Q K^T: wave w owns rows [16w,16w+16) x all 128 cols ----
    const int wave = tid >> 6;
    const int lane = tid & 63;
    const int row0 = wave * 16;
    const int lr   = lane & 15;
    const int lkb  = (lane >> 4) * 16;

    f32x4 acc[8];
    #pragma unroll
    for (int c = 0; c < 8; ++c) acc[c] = (f32x4){0.f, 0.f, 0.f, 0.f};

    const int arow = row0 + lr;
    const char* aBase = (const char*)Qs + arow * (DIM * 2);
    const int aswz = (arow & 7) << 4;

    #pragma unroll
    for (int ks = 0; ks < 8; ++ks) {
        const bf16x8 a = *(const bf16x8*)(aBase + ((ks * 64 + lkb) ^ aswz));
        #pragma unroll
        for (int c = 0; c < 8; ++c) {
            const int brow = c * 16 + lr;
            const bf16x8 bb = *(const bf16x8*)((const char*)Ks + brow * (DIM * 2)
                                               + ((ks * 64 + lkb) ^ ((brow & 7) << 4)));
            acc[c] = __builtin_amdgcn_mfma_f32_16x16x32_bf16(a, bb, acc[c], 0, 0, 0);
        }
    }

    // ---- row softmax-weighted score -> sigmoid gate ----
    // lane holds S[row0 + (lane>>4)*4 + r][c*16 + (lane&15)]
    #pragma unroll
    for (int r = 0; r < 4; ++r) {
        float m = acc[0][r];
        #pragma unroll
        for (int c = 1; c < 8; ++c) m = fmaxf(m, acc[c][r]);
        #pragma unroll
        for (int off = 1; off < 16; off <<= 1) m = fmaxf(m, __shfl_xor(m, off, 64));
        float se = 0.f, wsum = 0.f;
        #pragma unroll
        for (int c = 0; c < 8; ++c) {
            const float e = __expf(acc[c][r] - m);
            se += e; wsum += e * acc[c][r];
        }
        #pragma unroll
        for (int off = 1; off < 16; off <<= 1) {
            se   += __shfl_xor(se, off, 64);
            wsum += __shfl_xor(wsum, off, 64);
        }
        if ((lane & 15) == 0)
            wq[row0 + (lane >> 4) * 4 + r] = 1.f / (1.f + __expf(-(wsum / se)));
    }
    __syncthreads();

    // ---- out[dh*128+dd] = sum_i wq[i] * Q[i][dh*128+dd], Q from LDS bf16 ----
    const int dd   = tid & 127;
    const int part = tid >> 7;            // 4 parts x 32 rows
    const int dgl  = dh * 128 + dd;
    float sum = 0.f;
    #pragma unroll 8
    for (int i = part * 32; i < part * 32 + 32; ++i) {
        const short s = *(const short*)((const char*)Qs + i * (DIM * 2)
                                        + ((2 * dgl) ^ ((i & 7) << 4)));
        sum += wq[i] * bf2f(s);
    }
    red[part][dd] = sum;
    __syncthreads();
    if (tid < 128) {
        float* outp = out + (size_t)side * (NGRAPH * DIM) + (size_t)g * DIM + dh * 128;
        outp[tid] = red[0][tid] + red[1][tid] + red[2][tid] + red[3][tid];
    }
}

extern "C" void kernel_launch(void* const* d_in, const int* in_sizes, int n_in,
                              void* d_out, int out_size, void* d_ws, size_t ws_size,
                              hipStream_t stream) {
    const float* left  = (const float*)d_in[0];
    const float* right = (const float*)d_in[1];
    float* out = (float*)d_out;
    match_gate_kernel<<<256, 512, 0, stream>>>(left, right, out);
}